// Round 4
// baseline (762.319 us; speedup 1.0000x reference)
//
#include <hip/hip_runtime.h>
#include <math.h>
#include <stdint.h>

#define BN_EPS 1e-5f

typedef unsigned short u16;
typedef unsigned int u32;
typedef __attribute__((ext_vector_type(8))) short short8;
typedef __attribute__((ext_vector_type(4))) float f32x4;

// N=32, C=O=64, T=1024, V=25, K=9, S=3
// ws layout (bytes):
#define OFF_YCL 0u            // y channel-last bf16 [n][t*25+v][64c]  : 104857600 B
#define OFF_AWP 104857600u    // AwT frags [3][2][64][8] u16           : 6144 B
#define OFF_WGP 104863744u    // wg  frags [3][2][4][64][8] u16        : 24576 B
#define OFF_WTP 104888320u    // wt  frags [18][4][64][8] u16          : 73728 B
#define OFF_C1A 104962048u
#define OFF_C1B 104962304u
#define OFF_C2A 104962560u
#define OFF_C2B 104962816u

__device__ __forceinline__ u16 f2bf(float f) {
    u32 u = __float_as_uint(f);
    u = (u + 0x7FFFu + ((u >> 16) & 1u)) >> 16;
    return (u16)u;
}
__device__ __forceinline__ float bf2f(u16 h) { return __uint_as_float(((u32)h) << 16); }

#define MFMA16(a, b, c) __builtin_amdgcn_mfma_f32_16x16x32_bf16((a), (b), (c), 0, 0, 0)

// ---------------- prep: BN folding + fragment pre-packing ----------------
__global__ void prep_kernel(const float* __restrict__ A, const float* __restrict__ attn,
                            const float* __restrict__ wg, const float* __restrict__ bg,
                            const float* __restrict__ g1, const float* __restrict__ b1,
                            const float* __restrict__ m1, const float* __restrict__ v1,
                            const float* __restrict__ wt, const float* __restrict__ bt,
                            const float* __restrict__ g2, const float* __restrict__ b2,
                            const float* __restrict__ m2, const float* __restrict__ v2,
                            char* __restrict__ ws) {
    const int tid = threadIdx.x;
    u16* awp = (u16*)(ws + OFF_AWP);
    u16* wgp = (u16*)(ws + OFF_WGP);
    u16* wtp = (u16*)(ws + OFF_WTP);
    float* c1a = (float*)(ws + OFF_C1A);
    float* c1b = (float*)(ws + OFF_C1B);
    float* c2a = (float*)(ws + OFF_C2A);
    float* c2b = (float*)(ws + OFF_C2B);

    // AwT A-frags: [s][mf][lane][j]; A[m=v][k=w] = (A*attn)[w][v], zero-padded
    for (int i = tid; i < 3072; i += 512) {
        int j = i & 7, lane = (i >> 3) & 63, mf = (i >> 9) & 1, s = i >> 10;
        int v = mf * 16 + (lane & 15), w = (lane >> 4) * 8 + j;
        float val = 0.f;
        if (v < 25 && w < 25) val = A[(s * 25 + w) * 25 + v] * attn[(s * 25 + w) * 25 + v];
        awp[i] = f2bf(val);
    }
    // wg B-frags: [s][ks][ot][lane][j]; B[k=c][n=o] = wg[s][o][c]
    for (int i = tid; i < 12288; i += 512) {
        int j = i & 7, lane = (i >> 3) & 63, ot = (i >> 9) & 3, ks = (i >> 11) & 1, s = i >> 12;
        int c = ks * 32 + (lane >> 4) * 8 + j, o = ot * 16 + (lane & 15);
        wgp[i] = f2bf(wg[(s * 64 + o) * 64 + c]);
    }
    // wt B-frags: [ks][ot][lane][j]; kappa = tap*64 + c (tap-major K=576)
    for (int i = tid; i < 36864; i += 512) {
        int j = i & 7, lane = (i >> 3) & 63, ot = (i >> 9) & 3, ks = i >> 11;
        int kk = ks * 32 + (lane >> 4) * 8 + j;
        int tap = kk >> 6, c = kk & 63, o = ot * 16 + (lane & 15);
        wtp[i] = f2bf(wt[(o * 64 + c) * 9 + tap]);
    }
    if (tid < 64) {
        int o = tid;
        float inv1 = g1[o] * rsqrtf(v1[o] + BN_EPS);
        float bgsum = bg[o] + bg[64 + o] + bg[128 + o];
        c1a[o] = inv1;
        c1b[o] = bgsum * inv1 + b1[o] - m1[o] * inv1;
        float inv2 = g2[o] * rsqrtf(v2[o] + BN_EPS);
        c2a[o] = inv2;
        c2b[o] = bt[o] * inv2 + b2[o] - m2[o] * inv2;
    }
}

// ---------------- K1: graph conv (MFMA) + BN1 + residual + relu -> ycl ----------------
// Block: (n, 8-t tile) = 200 output cols, 8 waves, 59.4 KB LDS -> 2 blocks/CU.
__global__ __launch_bounds__(512, 4) void gcn_kernel(const float* __restrict__ x,
                                                     char* __restrict__ ws) {
    __shared__ u16 xwl[8 * 64 * 32];  // x tile [t][c][w32] bf16, swz ^((c&3)<<3)  32768 B
    __shared__ u16 aggL[208 * 64];    // agg [row=tv][c] bf16, swz ^((row&7)<<3)   26624 B
    const u16* awp = (const u16*)(ws + OFF_AWP);
    const u16* wgp = (const u16*)(ws + OFF_WGP);
    const float* c1a = (const float*)(ws + OFF_C1A);
    const float* c1b = (const float*)(ws + OFF_C1B);
    u16* ycl = (u16*)(ws + OFF_YCL);

    const int tid = threadIdx.x;
    const int lane = tid & 63;
    const int wv = tid >> 6;
    const int n = blockIdx.y, tb = blockIdx.x;
    const int t0 = tb * 8;

    // AwT A-fragments (6) into regs
    short8 a1[6];
#pragma unroll
    for (int i = 0; i < 6; ++i) a1[i] = *(const short8*)(awp + (i * 64 + lane) * 8);

    // BN consts per o-frag
    float sa[4], sb[4];
#pragma unroll
    for (int ot = 0; ot < 4; ++ot) {
        int o = ot * 16 + (lane & 15);
        sa[ot] = c1a[o];
        sb[ot] = c1b[o];
    }

    // stage x -> xwl: per c, 8t*25v = 200 contiguous floats = 50 float4 (coalesced)
    const size_t xbase = (size_t)n * 64 * 25600;
    for (int idx = tid; idx < 3200; idx += 512) {
        int c = idx / 50, r4 = idx - c * 50;
        f32x4 xv = *(const f32x4*)(x + xbase + (size_t)c * 25600 + t0 * 25 + r4 * 4);
#pragma unroll
        for (int e = 0; e < 4; ++e) {
            int tr = r4 * 4 + e;
            int t = tr / 25, v = tr - t * 25;
            xwl[((t * 64 + c) * 32 + v) ^ ((c & 3) << 3)] = f2bf(xv[e]);
        }
    }
    // zero pad w=25..31 (MFMA-1 reads them; Aw rows are zero but 0*NaN=NaN)
    for (int idx = tid; idx < 3584; idx += 512) {
        int t = idx / 448, rem = idx - t * 448;
        int c = rem / 7, v = 25 + (rem - c * 7);
        xwl[((t * 64 + c) * 32 + v) ^ ((c & 3) << 3)] = 0;
    }
    __syncthreads();

    f32x4 acc[2][4];
#pragma unroll
    for (int i = 0; i < 2; ++i)
#pragma unroll
        for (int j = 0; j < 4; ++j) acc[i][j] = {0.f, 0.f, 0.f, 0.f};

#pragma unroll
    for (int s = 0; s < 3; ++s) {
        // ---- MFMA-1: agg_s[v,c] for this wave's t = wv ----
        const int t = wv;
        f32x4 d[2][4];
#pragma unroll
        for (int mf = 0; mf < 2; ++mf)
#pragma unroll
            for (int nf = 0; nf < 4; ++nf) d[mf][nf] = {0.f, 0.f, 0.f, 0.f};
#pragma unroll
        for (int nf = 0; nf < 4; ++nf) {
            int c = nf * 16 + (lane & 15);
            int w0 = (lane >> 4) * 8;
            short8 b = *(const short8*)&xwl[((t * 64 + c) * 32 + w0) ^ ((c & 3) << 3)];
            d[0][nf] = MFMA16(a1[s * 2 + 0], b, d[0][nf]);
            d[1][nf] = MFMA16(a1[s * 2 + 1], b, d[1][nf]);
        }
        // wg B-frags for this s (independent of LDS state; overlaps MFMA-1 latency)
        short8 bw[2][4];
#pragma unroll
        for (int ks = 0; ks < 2; ++ks)
#pragma unroll
            for (int ot = 0; ot < 4; ++ot)
                bw[ks][ot] = *(const short8*)(wgp + (((s * 2 + ks) * 4 + ot) * 64 + lane) * 8);
#pragma unroll
        for (int mf = 0; mf < 2; ++mf)
#pragma unroll
            for (int nf = 0; nf < 4; ++nf)
#pragma unroll
                for (int r = 0; r < 4; ++r) {
                    int v = mf * 16 + (lane >> 4) * 4 + r;
                    if (v < 25) {
                        int row = t * 25 + v;
                        int c = nf * 16 + (lane & 15);
                        aggL[(row * 64 + c) ^ ((row & 7) << 3)] = f2bf(d[mf][nf][r]);
                    }
                }
        __syncthreads();
        // ---- MFMA-2: h += Wg_s . agg_s  (K=64); 13 m-frags over 8 waves ----
#pragma unroll
        for (int p = 0; p < 2; ++p) {
            if (p == 1 && wv >= 5) break;
            int mfr = (p == 0) ? wv : (8 + wv);
            int col = mfr * 16 + (lane & 15);
#pragma unroll
            for (int ks = 0; ks < 2; ++ks) {
                int c0 = ks * 32 + (lane >> 4) * 8;
                short8 a = *(const short8*)&aggL[(col * 64 + c0) ^ ((col & 7) << 3)];
#pragma unroll
                for (int ot = 0; ot < 4; ++ot) acc[p][ot] = MFMA16(a, bw[ks][ot], acc[p][ot]);
            }
        }
        __syncthreads();
    }

    // epilogue: BN1 + residual(x from xwl) + relu -> aggL (reuse)
#pragma unroll
    for (int p = 0; p < 2; ++p) {
        if (p == 1 && wv >= 5) break;
        int mfr = (p == 0) ? wv : (8 + wv);
#pragma unroll
        for (int ot = 0; ot < 4; ++ot) {
            int o = ot * 16 + (lane & 15);
#pragma unroll
            for (int r = 0; r < 4; ++r) {
                int row = mfr * 16 + (lane >> 4) * 4 + r;
                if (row < 200) {
                    int tl = row / 25, v = row - tl * 25;
                    float xr = bf2f(xwl[((tl * 64 + o) * 32 + v) ^ ((o & 3) << 3)]);
                    float val = fmaf(acc[p][ot][r], sa[ot], sb[ot]) + xr;
                    aggL[(row * 64 + o) ^ ((row & 7) << 3)] = f2bf(fmaxf(val, 0.f));
                }
            }
        }
    }
    __syncthreads();
    // copy -> global ycl (16B chunks, coalesced)
    const size_t ybase = ((size_t)n * 25600 + (size_t)t0 * 25) * 64;
    for (int idx = tid; idx < 1600; idx += 512) {
        int row = idx >> 3, cg = idx & 7;
        short8 vv = *(const short8*)&aggL[(row * 64 + cg * 8) ^ ((row & 7) << 3)];
        *(short8*)(ycl + ybase + row * 64 + cg * 8) = vv;
    }
}

// ---------------- K2: temporal conv (MFMA, K=576) + BN2 + residual + relu -> out ----------------
// Block: (n, 256-col tile), 8 waves x 32 cols, 58.4 KB LDS -> 2 blocks/CU.
__global__ __launch_bounds__(512, 4) void tcn_kernel(const float* __restrict__ x,
                                                     char* __restrict__ ws,
                                                     float* __restrict__ out) {
    __shared__ u16 ytile[456 * 64];  // [st][c] bf16, swz ^((st&7)<<3)  58368 B
    const u16* ycl = (const u16*)(ws + OFF_YCL);
    const u16* wtp = (const u16*)(ws + OFF_WTP);
    const float* c2a = (const float*)(ws + OFF_C2A);
    const float* c2b = (const float*)(ws + OFF_C2B);

    const int tid = threadIdx.x, lane = tid & 63, wv = tid >> 6;
    const int n = blockIdx.y, cb = blockIdx.x;
    const int col0 = cb * 256;
    const u16* yn = ycl + (size_t)n * 25600 * 64;

    float sa[4], sb[4];
#pragma unroll
    for (int ot = 0; ot < 4; ++ot) {
        int o = ot * 16 + (lane & 15);
        sa[ot] = c2a[o];
        sb[ot] = c2b[o];
    }

    // stage y tile with +-100 halo, zero OOB
    for (int idx = tid; idx < 3648; idx += 512) {
        int st = idx >> 3, cg = idx & 7;
        int gcol = col0 - 100 + st;
        short8 v = {0, 0, 0, 0, 0, 0, 0, 0};
        if (gcol >= 0 && gcol < 25600) v = *(const short8*)(yn + (size_t)gcol * 64 + cg * 8);
        *(short8*)&ytile[(st * 64 + cg * 8) ^ ((st & 7) << 3)] = v;
    }

    // prefetch B-frags for ks=0 while staging lands
    short8 Bc[4], Bn[4];
#pragma unroll
    for (int ot = 0; ot < 4; ++ot) Bc[ot] = *(const short8*)(wtp + (ot * 64 + lane) * 8);

    __syncthreads();

    f32x4 acc[2][4];
#pragma unroll
    for (int i = 0; i < 2; ++i)
#pragma unroll
        for (int j = 0; j < 4; ++j) acc[i][j] = {0.f, 0.f, 0.f, 0.f};

    const int st0 = wv * 32 + (lane & 15);
    const int c0g = (lane >> 4) * 8;

    for (int ks = 0; ks < 18; ++ks) {
        // prefetch next ks B-frags (global, L2-resident; overlaps MFMAs)
        if (ks < 17) {
#pragma unroll
            for (int ot = 0; ot < 4; ++ot)
                Bn[ot] = *(const short8*)(wtp + (((ks + 1) * 4 + ot) * 64 + lane) * 8);
        }
        const int tap = ks >> 1;
        const int c0 = (ks & 1) * 32 + c0g;
        short8 Af[2];
#pragma unroll
        for (int mf = 0; mf < 2; ++mf) {
            int st = st0 + mf * 16 + tap * 25;
            Af[mf] = *(const short8*)&ytile[(st * 64 + c0) ^ ((st & 7) << 3)];
        }
#pragma unroll
        for (int mf = 0; mf < 2; ++mf)
#pragma unroll
            for (int ot = 0; ot < 4; ++ot) acc[mf][ot] = MFMA16(Af[mf], Bc[ot], acc[mf][ot]);
#pragma unroll
        for (int ot = 0; ot < 4; ++ot) Bc[ot] = Bn[ot];
    }

    // epilogue: BN2 + residual(x fp32, contiguous) + relu -> out
    const size_t obase = (size_t)n * 64 * 25600;
#pragma unroll
    for (int mf = 0; mf < 2; ++mf)
#pragma unroll
        for (int ot = 0; ot < 4; ++ot) {
            int o = ot * 16 + (lane & 15);
            size_t rowb = obase + (size_t)o * 25600 +
                          (size_t)(col0 + wv * 32 + mf * 16 + (lane >> 4) * 4);
            f32x4 xv = *(const f32x4*)(x + rowb);
            f32x4 r;
#pragma unroll
            for (int e = 0; e < 4; ++e)
                r[e] = fmaxf(fmaf(acc[mf][ot][e], sa[ot], sb[ot]) + xv[e], 0.f);
            *(f32x4*)(out + rowb) = r;
        }
}

extern "C" void kernel_launch(void* const* d_in, const int* in_sizes, int n_in,
                              void* d_out, int out_size, void* d_ws, size_t ws_size,
                              hipStream_t stream) {
    const float* x = (const float*)d_in[0];
    const float* A = (const float*)d_in[1];
    const float* attn = (const float*)d_in[2];
    const float* wg = (const float*)d_in[3];
    const float* bg = (const float*)d_in[4];
    const float* g1 = (const float*)d_in[5];
    const float* b1 = (const float*)d_in[6];
    const float* m1 = (const float*)d_in[7];
    const float* v1 = (const float*)d_in[8];
    const float* wt = (const float*)d_in[9];
    const float* bt = (const float*)d_in[10];
    const float* g2 = (const float*)d_in[11];
    const float* b2 = (const float*)d_in[12];
    const float* m2 = (const float*)d_in[13];
    const float* v2 = (const float*)d_in[14];
    char* ws = (char*)d_ws;
    float* out = (float*)d_out;

    hipLaunchKernelGGL(prep_kernel, dim3(1), dim3(512), 0, stream, A, attn, wg, bg, g1, b1, m1,
                       v1, wt, bt, g2, b2, m2, v2, ws);
    hipLaunchKernelGGL(gcn_kernel, dim3(128, 32), dim3(512), 0, stream, x, ws);
    hipLaunchKernelGGL(tcn_kernel, dim3(100, 32), dim3(512), 0, stream, x, ws, out);
}